// Round 1
// baseline (206.320 us; speedup 1.0000x reference)
//
#include <hip/hip_runtime.h>

#define IMG_H 512
#define IMG_W 512

__device__ __forceinline__ int reflect512(int t) {
    t = (t < 0) ? -t : t;
    t = (t > 511) ? 1022 - t : t;
    return t;
}

// 64-thread (1-wave) blocks; each wave computes a 64x64 output tile by
// streaming 74 rows (10-row halo): horizontal 11-tap blur from a tiny LDS
// row buffer, vertical 11-tap blur from a register ring (static indices
// after full unroll), fused SSIM epilogue.
__global__ __launch_bounds__(64, 3) void ssim_kernel(
    const float* __restrict__ img1,
    const float* __restrict__ img2,
    float* __restrict__ out)
{
    // gaussian(11, sigma=1.5), L1-normalized
    const float kW[11] = {
        0.00102838f, 0.00759876f, 0.03600078f, 0.10936055f, 0.21300561f,
        0.26601182f, 0.21300561f, 0.10936055f, 0.03600078f, 0.00759876f,
        0.00102838f };
    const float C1 = 0.0001f;  // (0.01*1)^2
    const float C2 = 0.0009f;  // (0.03*1)^2

    const int lane = threadIdx.x;
    const int x0 = blockIdx.x * 64;
    const int y0 = blockIdx.y * 64;
    const size_t pbase = (size_t)blockIdx.z * (IMG_H * IMG_W);
    const float* __restrict__ p1 = img1 + pbase;
    const float* __restrict__ p2 = img2 + pbase;
    float* __restrict__ po = out + pbase;

    __shared__ float2 buf[2][80];   // 74 used per row, double-buffered

    // 11-deep register rings for the 5 horizontally-blurred quantities
    float r1[11], r2[11], r11[11], r22[11], r12[11];

    const int x = x0 + lane;
    const int gx0 = reflect512(x0 - 5 + lane);        // all 64 lanes
    const int gx1 = reflect512(x0 - 5 + lane + 64);   // lanes 0..9 only

    for (int sb = 0; sb < 74; sb += 11) {
        #pragma unroll
        for (int r = 0; r < 11; ++r) {
            const int s = sb + r;          // row step 0..73 (uniform)
            if (s < 74) {
                // ---- stage reflected row s of both images into LDS ----
                const int gy = reflect512(y0 - 5 + s);
                const float* row1 = p1 + (size_t)gy * IMG_W;
                const float* row2 = p2 + (size_t)gy * IMG_W;
                float2* b = buf[s & 1];
                b[lane] = make_float2(row1[gx0], row2[gx0]);
                if (lane < 10)
                    b[lane + 64] = make_float2(row1[gx1], row2[gx1]);
                __syncthreads();

                // ---- horizontal 11-tap blur of {a, b, a^2, b^2, ab} ----
                float h1 = 0.f, h2 = 0.f, h11 = 0.f, h22 = 0.f, h12 = 0.f;
                #pragma unroll
                for (int k = 0; k < 11; ++k) {
                    const float2 t = b[lane + k];
                    const float wk = kW[k];
                    const float ta = wk * t.x;
                    const float tb = wk * t.y;
                    h1 += ta;
                    h2 += tb;
                    h11 = fmaf(ta, t.x, h11);
                    h22 = fmaf(tb, t.y, h22);
                    h12 = fmaf(ta, t.y, h12);
                }
                r1[r] = h1; r2[r] = h2; r11[r] = h11; r22[r] = h22; r12[r] = h12;

                // ---- vertical 11-tap blur + SSIM epilogue ----
                if (s >= 10) {
                    float v1 = 0.f, v2 = 0.f, v11 = 0.f, v22 = 0.f, v12 = 0.f;
                    #pragma unroll
                    for (int d = 0; d < 11; ++d) {
                        const int slot = (r + 11 - d) % 11;  // static after unroll
                        const float wd = kW[10 - d];
                        v1  = fmaf(wd, r1[slot],  v1);
                        v2  = fmaf(wd, r2[slot],  v2);
                        v11 = fmaf(wd, r11[slot], v11);
                        v22 = fmaf(wd, r22[slot], v22);
                        v12 = fmaf(wd, r12[slot], v12);
                    }
                    const float mu1s = v1 * v1;
                    const float mu2s = v2 * v2;
                    const float mu12 = v1 * v2;
                    const float sg1  = v11 - mu1s;
                    const float sg2  = v22 - mu2s;
                    const float sg12 = v12 - mu12;
                    const float num = fmaf(2.f, mu12, C1) * fmaf(2.f, sg12, C2);
                    const float den = (mu1s + mu2s + C1) * (sg1 + sg2 + C2);
                    float rden = __builtin_amdgcn_rcpf(den);
                    rden = rden * (2.f - den * rden);   // 1 Newton step
                    const float ssim = num * rden;
                    const float loss = 0.5f * fminf(fmaxf(1.f - ssim, 0.f), 1.f);
                    po[(size_t)(y0 + s - 10) * IMG_W + x] = loss;
                }
            }
        }
    }
}

extern "C" void kernel_launch(void* const* d_in, const int* in_sizes, int n_in,
                              void* d_out, int out_size, void* d_ws, size_t ws_size,
                              hipStream_t stream) {
    const float* img1 = (const float*)d_in[0];
    const float* img2 = (const float*)d_in[1];
    float* out = (float*)d_out;
    dim3 grid(IMG_W / 64, IMG_H / 64, 48);   // 8 x 8 x (16*3) = 3072 one-wave blocks
    ssim_kernel<<<grid, dim3(64, 1, 1), 0, stream>>>(img1, img2, out);
}